// Round 9
// baseline (11938.800 us; speedup 1.0000x reference)
//
#include <hip/hip_runtime.h>
#include <hip/hip_bf16.h>
#include <stdint.h>

// LSTM bidirectional 2-layer, T=512 B=64 D=H=512.
// prep(cast+bias+ring-init) -> gemm_xg(L0) -> rec(L0) -> gemm_xg(L1) -> rec(L1).
// R7: single-hop sync on a COMPACT 512KB ring with per-u16 tag-in-data
//   (h in [-1,1] => fp16 bit14 always 0). Orthogonal per-layer tag alphabets:
//   L0 {0000,1111}, L1 {1010,0101}, ring init = neutral 0011 (matches nothing).
// R12: BARRIER-FREE single-wave consumers. R9 vs R11 identical dur despite
//   different schedules => shared intra-WG fabric (4 barriers/iter, LDS stage
//   with 3.7e7 conflict-cycles, 2-wave pointwise) is the bottleneck, not sync
//   topology. New shape: 512 WGs x 64 thr (1 wave), WG = (bh, 4 h-cols, BOTH
//   dirs). The 16 tagged 16B ring loads ARE the MFMA A-frags (L3 -> registers,
//   no LDS); gate regroup is an intra-wave shfl_xor butterfly (R10-verified);
//   h writeback is one 2B tagged atomic per lane. ZERO __syncthreads, ZERO LDS.
//   Weights (both dirs) live in AGPRs (launch_bounds(64,2) caps VGPR at 256 ->
//   compiler promotes, as proven in R9). A/B chains alternate: each chain's
//   loads issued ~half-iter before check. Tag check self-validates every u16,
//   so loose vmcnt counts / early returns degrade to retries, never corruption.
// R5 carry-over: xg stores/loads non-temporal (268MB read-once stream).

typedef __attribute__((ext_vector_type(8))) _Float16 half8;
typedef __attribute__((ext_vector_type(4))) float f32x4;
typedef __attribute__((ext_vector_type(4))) uint32_t u32x4;
typedef unsigned long long ull;

#define TM32    0x40004000u
#define TAGU16  ((unsigned short)0x4000)
// neutral ring-init pattern (halves 0,1 of each 8B): matches no expectation
#define PAT_INIT_LO 0x40004000u
#define PAT_INIT_HI 0x00000000u

__device__ __forceinline__ unsigned short f2h(float f) {
    union { _Float16 h; unsigned short u; } c; c.h = (_Float16)f; return c.u;
}
__device__ __forceinline__ float h2f(unsigned short u) {
    union { _Float16 h; unsigned short u; } c; c.u = u; return (float)c.h;
}

// ---------------- prep: casts, bias sums, ring init (neutral pattern) ----------------
__global__ __launch_bounds__(256) void prep_kernel(
    const float* __restrict__ x,
    const float* __restrict__ w0f, const float* __restrict__ w0b,
    const float* __restrict__ w1f, const float* __restrict__ w1b,
    const float* __restrict__ bi0f, const float* __restrict__ bh0f,
    const float* __restrict__ bi0b, const float* __restrict__ bh0b,
    const float* __restrict__ bi1f, const float* __restrict__ bh1f,
    const float* __restrict__ bi1b, const float* __restrict__ bh1b,
    unsigned short* __restrict__ xh,
    unsigned short* __restrict__ wihh,
    float* __restrict__ bias,
    uint32_t* __restrict__ hbufi)          // ring init: 512KB neutral pattern
{
    const long total = 5801984L;   // units of 16B quads
    long stride = (long)gridDim.x * blockDim.x;
    for (long i = (long)blockIdx.x * blockDim.x + threadIdx.x; i < total; i += stride) {
        if (i < 4194304L) {                       // x: fp32 -> fp16 (16.78M elems)
            float4 v = ((const float4*)x)[i];
            ushort4 o; o.x=f2h(v.x); o.y=f2h(v.y); o.z=f2h(v.z); o.w=f2h(v.w);
            ((ushort4*)xh)[i] = o;
        } else if (i < 5767168L) {                // w_ih casts: [w0f][w0b][w1f][w1b]
            long j = i - 4194304L;
            const float* src; long sq;
            if (j < 262144L)       { src = w0f; sq = j;            }
            else if (j < 524288L)  { src = w0b; sq = j - 262144L;  }
            else if (j < 1048576L) { src = w1f; sq = j - 524288L;  }
            else                   { src = w1b; sq = j - 1048576L; }
            float4 v = ((const float4*)src)[sq];
            ushort4 o; o.x=f2h(v.x); o.y=f2h(v.y); o.z=f2h(v.z); o.w=f2h(v.w);
            ((ushort4*)wihh)[j] = o;
        } else if (i < 5769216L) {                // bias sums: b_ih + b_hh, 4 x 2048 fp32
            long j = i - 5767168L;                // 0..2047 quads
            int ld = (int)(j >> 9);
            long cq = j & 511L;
            const float* bi = ld==0?bi0f: ld==1?bi0b: ld==2?bi1f:bi1b;
            const float* bh = ld==0?bh0f: ld==1?bh0b: ld==2?bh1f:bh1b;
            float4 a = ((const float4*)bi)[cq];
            float4 b = ((const float4*)bh)[cq];
            float4 o; o.x=a.x+b.x; o.y=a.y+b.y; o.z=a.z+b.z; o.w=a.w+b.w;
            ((float4*)bias)[ld*512 + cq] = o;
        } else {                                  // ring init: 32768 quads = 512KB
            long j = i - 5769216L;
            uint4 p; p.x=PAT_INIT_LO; p.y=PAT_INIT_HI; p.z=PAT_INIT_LO; p.w=PAT_INIT_HI;
            ((uint4*)hbufi)[j] = p;
        }
    }
}

// ---------------- xg GEMM: xg = A @ W^T, fp16 out, TRANSPOSED layout ----------------
__global__ __launch_bounds__(256) void gemm_xg(
    const unsigned short* __restrict__ A,
    const unsigned short* __restrict__ Wf,
    const unsigned short* __restrict__ Wb,
    unsigned short* __restrict__ xg,
    int Din)
{
    __shared__ __align__(16) unsigned short As[4096];   // 128 rows x 32 k, fp16
    __shared__ __align__(16) unsigned short Bs[4096];
    const int dir = blockIdx.z;
    const unsigned short* W = dir ? Wb : Wf;
    unsigned short* out = xg + (size_t)dir * 32768 * 2048;
    const int bn = blockIdx.x, bm = blockIdx.y;
    const int tid = threadIdx.x;
    const int wave = tid >> 6, lane = tid & 63;
    const int q = lane >> 4, ln = lane & 15;
    const int wm = wave >> 1, wn = wave & 1;

    f32x4 acc[4][4];
#pragma unroll
    for (int a = 0; a < 4; ++a)
#pragma unroll
        for (int b = 0; b < 4; ++b) acc[a][b] = (f32x4){0.f, 0.f, 0.f, 0.f};

    const int kiter = Din >> 5;
    for (int kb = 0; kb < kiter; ++kb) {
        __syncthreads();
#pragma unroll
        for (int i = 0; i < 2; ++i) {
            int off = i*4096 + wave*1024 + lane*16;   // byte offset in 8KB tile
            int row = off >> 6;
            int kel = (off & 63) >> 1;
            const unsigned short* sa = A + (size_t)(bm*128 + row)*Din + kb*32 + kel;
            const unsigned short* sb = W + (size_t)(bn*128 + row)*Din + kb*32 + kel;
            __builtin_amdgcn_global_load_lds(
                (const __attribute__((address_space(1))) uint32_t*)sa,
                (__attribute__((address_space(3))) uint32_t*)((char*)As + i*4096 + wave*1024),
                16, 0, 0);
            __builtin_amdgcn_global_load_lds(
                (const __attribute__((address_space(1))) uint32_t*)sb,
                (__attribute__((address_space(3))) uint32_t*)((char*)Bs + i*4096 + wave*1024),
                16, 0, 0);
        }
        __syncthreads();
        half8 af[4], bf[4];
#pragma unroll
        for (int mt = 0; mt < 4; ++mt)
            af[mt] = *(const half8*)((const char*)As + (wm*64 + mt*16 + ln)*64 + q*16);
#pragma unroll
        for (int nt = 0; nt < 4; ++nt)
            bf[nt] = *(const half8*)((const char*)Bs + (wn*64 + nt*16 + ln)*64 + q*16);
#pragma unroll
        for (int mt = 0; mt < 4; ++mt)
#pragma unroll
            for (int nt = 0; nt < 4; ++nt)
                acc[mt][nt] = __builtin_amdgcn_mfma_f32_16x16x32_f16(af[mt], bf[nt], acc[mt][nt], 0, 0, 0);
    }
    const int tt = bm*2 + wm;
#pragma unroll
    for (int mt = 0; mt < 4; ++mt)
#pragma unroll
        for (int nt = 0; nt < 4; ++nt) {
            int col = bn*128 + wn*64 + nt*16 + ln;
            int gate = col >> 9, colg = col & 511;
            union { unsigned short u[4]; ull v; } p;
#pragma unroll
            for (int r = 0; r < 4; ++r) p.u[r] = f2h(acc[mt][nt][r]);
            __builtin_nontemporal_store(p.v,
                (ull*)(out + (((size_t)tt*4 + gate)*512 + colg)*64 + mt*16 + q*4));
        }
}

// ---- asm helpers: tagged 16B ring loads (offset walks kk), tag-checked ----
#define LDQ(d, b, o) \
    asm volatile("global_load_dwordx4 %0, %1, off offset:" o " sc0 sc1" \
                 : "=v"(d) : "v"(b) : "memory");

#define ISSUE16(hq, base) \
    LDQ(hq[0],  base, "0")   LDQ(hq[1],  base, "64")  LDQ(hq[2],  base, "128") \
    LDQ(hq[3],  base, "192") LDQ(hq[4],  base, "256") LDQ(hq[5],  base, "320") \
    LDQ(hq[6],  base, "384") LDQ(hq[7],  base, "448") LDQ(hq[8],  base, "512") \
    LDQ(hq[9],  base, "576") LDQ(hq[10], base, "640") LDQ(hq[11], base, "704") \
    LDQ(hq[12], base, "768") LDQ(hq[13], base, "832") LDQ(hq[14], base, "896") \
    LDQ(hq[15], base, "960")

#define RETRY16(hq, base, bm) \
    if (bm & 0x0001u) LDQ(hq[0],  base, "0")   if (bm & 0x0002u) LDQ(hq[1],  base, "64") \
    if (bm & 0x0004u) LDQ(hq[2],  base, "128") if (bm & 0x0008u) LDQ(hq[3],  base, "192") \
    if (bm & 0x0010u) LDQ(hq[4],  base, "256") if (bm & 0x0020u) LDQ(hq[5],  base, "320") \
    if (bm & 0x0040u) LDQ(hq[6],  base, "384") if (bm & 0x0080u) LDQ(hq[7],  base, "448") \
    if (bm & 0x0100u) LDQ(hq[8],  base, "512") if (bm & 0x0200u) LDQ(hq[9],  base, "576") \
    if (bm & 0x0400u) LDQ(hq[10], base, "640") if (bm & 0x0800u) LDQ(hq[11], base, "704") \
    if (bm & 0x1000u) LDQ(hq[12], base, "768") if (bm & 0x2000u) LDQ(hq[13], base, "832") \
    if (bm & 0x4000u) LDQ(hq[14], base, "896") if (bm & 0x8000u) LDQ(hq[15], base, "960")

#define TB(qq, ep) ((((qq)[0]^(ep)) | ((qq)[1]^(ep)) | ((qq)[2]^(ep)) | ((qq)[3]^(ep))) & TM32)

// ---------------- recurrent kernel: barrier-free, 1 wave per WG ----------------
// 512 WGs x 64 thr. WG = (bh: 16 batch rows, cg: 4 h-cols), BOTH dirs (chains
// A=fwd, B=bwd alternate). Lane (q=lane>>4, ln=lane&15); B-col n=ln maps to
// (gate=ln&3, col=C0+(ln>>2)). A-frag row = ln, k = kk*32+q*8 (= the 16B load).
__global__ __launch_bounds__(64, 2) void rec_kernel(
    const unsigned short* __restrict__ xg,    // [dir][t][gate][hcol][brow] fp16, bias-free
    const float* __restrict__ whhf,           // [2048][512] fp32
    const float* __restrict__ whhb,
    const float* __restrict__ bias,           // [2 dir][2048] fp32 (b_ih+b_hh)
    unsigned short* __restrict__ hbuf,        // ring [4 slot][2 dir][64][512] fp16, tagged
    unsigned short* __restrict__ outh,        // layer0: in1 [T][64][1024] fp16
    float* __restrict__ outf,                 // layer1: d_out fp32 [T][64][1024]
    const int layer)
{
    const int bx = blockIdx.x;                 // 512 WGs
    const int bh = bx & 3, cg = bx >> 2;       // cg 0..127
    const int R0 = bh*16, C0 = cg*4;
    const int lane = threadIdx.x;
    const int ln = lane & 15, q = lane >> 4;
    const int gate = ln & 3, lc = ln >> 2;
    const int colg = C0 + lc;

    // per-layer tag alphabet. expected dword patterns:
    const uint32_t ep0 = layer ? 0x00004000u : 0u;          // parity 0
    const uint32_t ep1 = layer ? 0x40000000u : TM32;        // parity 1
    // writer per-u16 tag (depends on col parity for L1):
    const unsigned short wt0 = layer ? ((colg & 1) ? (unsigned short)0 : TAGU16)
                                     : (unsigned short)0;
    const unsigned short wt1 = layer ? ((colg & 1) ? TAGU16 : (unsigned short)0)
                                     : TAGU16;

    // ---- W_hh -> registers (AGPR-promoted), both dirs: 16 half8 each ----
    half8 wregA[16], wregB[16];
    {
        const float* srcA = whhf + (size_t)(gate*512 + colg)*512 + q*8;
        const float* srcB = whhb + (size_t)(gate*512 + colg)*512 + q*8;
#pragma unroll
        for (int kk = 0; kk < 16; ++kk) {
            float4 v0 = *(const float4*)(srcA + kk*32);
            float4 v1 = *(const float4*)(srcA + kk*32 + 4);
            union { unsigned short u[8]; half8 v; } p;
            p.u[0]=f2h(v0.x); p.u[1]=f2h(v0.y); p.u[2]=f2h(v0.z); p.u[3]=f2h(v0.w);
            p.u[4]=f2h(v1.x); p.u[5]=f2h(v1.y); p.u[6]=f2h(v1.z); p.u[7]=f2h(v1.w);
            wregA[kk] = p.v;
        }
#pragma unroll
        for (int kk = 0; kk < 16; ++kk) {
            float4 v0 = *(const float4*)(srcB + kk*32);
            float4 v1 = *(const float4*)(srcB + kk*32 + 4);
            union { unsigned short u[8]; half8 v; } p;
            p.u[0]=f2h(v0.x); p.u[1]=f2h(v0.y); p.u[2]=f2h(v0.z); p.u[3]=f2h(v0.w);
            p.u[4]=f2h(v1.x); p.u[5]=f2h(v1.y); p.u[6]=f2h(v1.z); p.u[7]=f2h(v1.w);
            wregB[kk] = p.v;
        }
    }

    const unsigned short* xgdA = xg;
    const unsigned short* xgdB = xg + (size_t)32768 * 2048;
    const float bvA = bias[gate*512 + colg];
    const float bvB = bias[2048 + gate*512 + colg];
    float carrA[4] = {0.f,0.f,0.f,0.f}, carrB[4] = {0.f,0.f,0.f,0.f};

    // A-frag load base: ring row R0+ln, u16 col q*8; kk walks via offset:kk*64
    #define RINGBASE(d, sm1) ((const uint32_t*)((const char*)hbuf \
        + ((size_t)(((sm1) & 3)*2 + (d))*64 + R0 + ln)*1024 + q*16))
    #define XGA(t) ((const ull*)(xgdA + ((size_t)((t)*4 + gate)*512 + colg)*64 + bh*16 + q*4))
    #define XGB(t) ((const ull*)(xgdB + ((size_t)((t)*4 + gate)*512 + colg)*64 + bh*16 + q*4))

    u32x4 hqA[16], hqB[16];
    ull xvA, xvB, xvAn, xvBn;

    // ---- pointwise as a macro over locals (no lambdas: R10 spill lesson) ----
    // acc[r] = pre-act for (gate,colg,row q*4+r); butterfly regroups gates
    // intra-wave (R10-verified); every lane stores h for row q*4+gate, col colg.
#define PW(accv, xv, carr, bv, d, s, t) {                                         \
        unsigned short hs[4];                                                     \
_Pragma("unroll")                                                                 \
        for (int r = 0; r < 4; ++r) {                                             \
            float v  = (accv)[r] + h2f((unsigned short)((xv) >> (16*r))) + (bv);  \
            float o1 = __shfl_xor(v, 1);                                          \
            float e  = (gate & 1) ? o1 : v;                                       \
            float od = (gate & 1) ? v  : o1;                                      \
            float e2 = __shfl_xor(e, 2);                                          \
            float od2= __shfl_xor(od, 2);                                         \
            float gi = (gate & 2) ? e2 : e;                                       \
            float gg = (gate & 2) ? e  : e2;                                      \
            float gf = (gate & 2) ? od2: od;                                      \
            float go = (gate & 2) ? od : od2;                                     \
            float si = 1.f / (1.f + __expf(-gi));                                 \
            float sf = 1.f / (1.f + __expf(-gf));                                 \
            float so = 1.f / (1.f + __expf(-go));                                 \
            float tg = 2.f / (1.f + __expf(-2.f*gg)) - 1.f;                       \
            float c  = sf * (carr)[r] + si * tg;                                  \
            (carr)[r] = c;                                                        \
            float th = 2.f / (1.f + __expf(-2.f*c)) - 1.f;                        \
            hs[r] = f2h(so * th);                                                 \
        }                                                                         \
        const int row = R0 + q*4 + gate;                                          \
        unsigned short hv = hs[gate];                                             \
        unsigned short tg16 = hv | ((((s) >> 2) & 1) ? wt1 : wt0);                \
        __hip_atomic_store(hbuf + ((size_t)(((s) & 3)*2 + (d))*64 + row)*512 + colg, \
                           tg16, __ATOMIC_RELAXED, __HIP_MEMORY_SCOPE_AGENT);     \
        if (layer == 0) {                                                         \
            __builtin_nontemporal_store(hv,                                       \
                outh + ((size_t)(t)*64 + row)*1024 + (d)*512 + colg);             \
        } else {                                                                  \
            __builtin_nontemporal_store(h2f(hv),                                  \
                outf + ((size_t)(t)*64 + row)*1024 + (d)*512 + colg);             \
        }                                                                         \
    }

#define CHECKB(hq, ep, bmv) { bmv = 0u;                                           \
_Pragma("unroll")                                                                 \
        for (int k = 0; k < 16; ++k) bmv |= TB(hq[k], ep) ? (1u << k) : 0u; }

#define RETRYLOOP(hq, base, ep, bmv) {                                            \
        int it_ = 0;                                                              \
        while (__builtin_expect(bmv != 0u, 0) && it_++ < 8192) {                  \
            RETRY16(hq, base, bmv)                                                \
            asm volatile("s_waitcnt vmcnt(0)" ::: "memory");                      \
            __builtin_amdgcn_sched_barrier(0);                                    \
            CHECKB(hq, ep, bmv)                                                   \
        } }

#define CLEAR16(hq) {                                                             \
_Pragma("unroll")                                                                 \
        for (int k = 0; k < 16; ++k) {                                            \
            hq[k][0] &= ~TM32; hq[k][1] &= ~TM32;                                 \
            hq[k][2] &= ~TM32; hq[k][3] &= ~TM32; } }

#define MFMA16(hq, wreg, accv) {                                                  \
        f32x4 a0_ = (f32x4){0.f,0.f,0.f,0.f}, a1_ = a0_;                          \
_Pragma("unroll")                                                                 \
        for (int k = 0; k < 16; k += 2) {                                         \
            union { u32x4 u; half8 h; } t0_, t1_;                                 \
            t0_.u = hq[k]; t1_.u = hq[k+1];                                       \
            a0_ = __builtin_amdgcn_mfma_f32_16x16x32_f16(t0_.h, wreg[k],   a0_, 0, 0, 0); \
            a1_ = __builtin_amdgcn_mfma_f32_16x16x32_f16(t1_.h, wreg[k+1], a1_, 0, 0, 0); \
        }                                                                         \
        accv = a0_ + a1_; }

    // ---- prologue: s=0 both chains (acc = 0), then issue A(1)-loads ----
    {
        xvA = __builtin_nontemporal_load(XGA(0));
        xvB = __builtin_nontemporal_load(XGB(511));
        f32x4 z = (f32x4){0.f,0.f,0.f,0.f};
        PW(z, xvA, carrA, bvA, 0, 0, 0)
        PW(z, xvB, carrB, bvB, 1, 0, 511)
        xvA = __builtin_nontemporal_load(XGA(1));
        xvB = __builtin_nontemporal_load(XGB(510));
        const uint32_t* baseA = RINGBASE(0, 0);
        ISSUE16(hqA, baseA)
    }

    // ---- main loop: no barriers; chains alternate to hide L3 latency ----
#pragma unroll 1
    for (int s = 1; s < 512; ++s) {
        const uint32_t ep = (((s - 1) >> 2) & 1) ? ep1 : ep0;
        const uint32_t* baseA = RINGBASE(0, s - 1);
        const uint32_t* baseB = RINGBASE(1, s - 1);
        uint32_t bm;

        // [1] check A (loads issued late last iter; ~B-phase of slack)
        asm volatile("s_waitcnt vmcnt(4)" ::: "memory");   // tolerate pwB stores + 2 xg
        __builtin_amdgcn_sched_barrier(0);
        CHECKB(hqA, ep, bm)
        RETRYLOOP(hqA, baseA, ep, bm)
        // [2] mfma A (A-frags direct from registers)
        CLEAR16(hqA)
        f32x4 accA; MFMA16(hqA, wregA, accA)
        // [3] issue B loads (hqA free... hqB separate; latency hides under pwA)
        ISSUE16(hqB, baseB)
        // [4] pointwise A + tagged ring store + out store
        PW(accA, xvA, carrA, bvA, 0, s, s)
        // [5] issue A(s+1) loads (after own A-store: program order)
        if (s < 511) { const uint32_t* baseA2 = RINGBASE(0, s); ISSUE16(hqA, baseA2) }
        // [6] check B (slack = pwA; newer-than-B = 2 pwA stores + 16 A-loads)
        asm volatile("s_waitcnt vmcnt(18)" ::: "memory");
        __builtin_amdgcn_sched_barrier(0);
        CHECKB(hqB, ep, bm)
        RETRYLOOP(hqB, baseB, ep, bm)
        // [7] mfma B
        CLEAR16(hqB)
        f32x4 accB; MFMA16(hqB, wregB, accB)
        // [8] pointwise B + stores; then xg prefetch for s+1
        PW(accB, xvB, carrB, bvB, 1, s, 511 - s)
        if (s < 511) {
            xvAn = __builtin_nontemporal_load(XGA(s + 1));
            xvBn = __builtin_nontemporal_load(XGB(510 - s));
            xvA = xvAn; xvB = xvBn;
        }
    }
}

extern "C" void kernel_launch(void* const* d_in, const int* in_sizes, int n_in,
                              void* d_out, int out_size, void* d_ws, size_t ws_size,
                              hipStream_t stream)
{
    (void)in_sizes; (void)n_in; (void)out_size; (void)ws_size;
    const float* x       = (const float*)d_in[0];
    const float* w_ih0_f = (const float*)d_in[1];
    const float* w_hh0_f = (const float*)d_in[2];
    const float* b_ih0_f = (const float*)d_in[3];
    const float* b_hh0_f = (const float*)d_in[4];
    const float* w_ih0_b = (const float*)d_in[5];
    const float* w_hh0_b = (const float*)d_in[6];
    const float* b_ih0_b = (const float*)d_in[7];
    const float* b_hh0_b = (const float*)d_in[8];
    const float* w_ih1_f = (const float*)d_in[9];
    const float* w_hh1_f = (const float*)d_in[10];
    const float* b_ih1_f = (const float*)d_in[11];
    const float* b_hh1_f = (const float*)d_in[12];
    const float* w_ih1_b = (const float*)d_in[13];
    const float* w_hh1_b = (const float*)d_in[14];
    const float* b_ih1_b = (const float*)d_in[15];
    const float* b_hh1_b = (const float*)d_in[16];

    // workspace layout (bytes): xg 256MB | wih_h 12MB | bias 32KB | hbuf ring 512KB
    char* ws = (char*)d_ws;
    unsigned short* xg    = (unsigned short*)(ws + 0);
    unsigned short* wihh  = (unsigned short*)(ws + 268435456L);
    float*          bias  = (float*)         (ws + 281018368L);
    unsigned short* hbuf  = (unsigned short*)(ws + 281051136L);

    // scratch stashed inside d_out (consumed before final output is written):
    unsigned short* in1 = (unsigned short*)d_out;                      // 67MB fp16 [T][64][1024]
    unsigned short* xh  = (unsigned short*)((char*)d_out + 67108864L); // 33.5MB fp16 x
    float* outf = (float*)d_out;

    prep_kernel<<<dim3(1024), dim3(256), 0, stream>>>(
        x, w_ih0_f, w_ih0_b, w_ih1_f, w_ih1_b,
        b_ih0_f, b_hh0_f, b_ih0_b, b_hh0_b,
        b_ih1_f, b_hh1_f, b_ih1_b, b_hh1_b,
        xh, wihh, bias, (uint32_t*)hbuf);

    // layer 0 (tag alphabet {0000,1111})
    gemm_xg<<<dim3(16, 256, 2), dim3(256), 0, stream>>>(
        xh, wihh, wihh + 1048576, xg, 512);
    rec_kernel<<<dim3(512), dim3(64), 0, stream>>>(
        xg, w_hh0_f, w_hh0_b, bias, hbuf, in1, (float*)nullptr, 0);

    // layer 1 (tag alphabet {1010,0101} — orthogonal to L0 residue and to init)
    gemm_xg<<<dim3(16, 256, 2), dim3(256), 0, stream>>>(
        in1, wihh + 2097152, wihh + 4194304, xg, 1024);
    rec_kernel<<<dim3(512), dim3(64), 0, stream>>>(
        xg, w_hh1_f, w_hh1_b, bias + 4096, hbuf,
        (unsigned short*)nullptr, outf, 1);
}